// Round 2
// baseline (437.578 us; speedup 1.0000x reference)
//
#include <hip/hip_runtime.h>
#include <hip/hip_bf16.h>
#include <cstdint>

#define BB 8
#define SS 2048
#define DD 1024
#define HH 1024

typedef __bf16 bf16x8 __attribute__((ext_vector_type(8)));
typedef float f32x4 __attribute__((ext_vector_type(4)));

// address-space casts for global_load_lds (direct global->LDS DMA)
#define AS1C(p) ((const __attribute__((address_space(1))) void*)(p))
#define AS3(p)  ((__attribute__((address_space(3))) void*)(p))

__device__ __forceinline__ float bf2f(uint16_t h) {
  union { uint32_t u; float f; } v; v.u = ((uint32_t)h) << 16; return v.f;
}
__device__ __forceinline__ uint16_t f2bf(float f) {
  union { float f; uint32_t u; } v; v.f = f;
  uint32_t u = v.u;
  return (uint16_t)((u + 0x7FFFu + ((u >> 16) & 1u)) >> 16);
}

// raw workgroup barrier WITHOUT the vmcnt(0) drain __syncthreads() emits.
// asm memory clobbers pin compiler-visible memory ops on both sides.
__device__ __forceinline__ void wgbar() {
  asm volatile("" ::: "memory");
  __builtin_amdgcn_s_barrier();
  asm volatile("" ::: "memory");
}

// fp32 -> bf16 (RNE), vectorized 8 elems/thread, grid-stride. n % 8 == 0.
__global__ void cvt_f32_bf16(const float* __restrict__ src,
                             uint16_t* __restrict__ dst, int n) {
  int i = (blockIdx.x * blockDim.x + threadIdx.x) * 8;
  const int stride = gridDim.x * blockDim.x * 8;
  for (; i < n; i += stride) {
    float4 f0 = *(const float4*)(src + i);
    float4 f1 = *(const float4*)(src + i + 4);
    alignas(16) uint16_t o[8];
    o[0] = f2bf(f0.x); o[1] = f2bf(f0.y); o[2] = f2bf(f0.z); o[3] = f2bf(f0.w);
    o[4] = f2bf(f1.x); o[5] = f2bf(f1.y); o[6] = f2bf(f1.z); o[7] = f2bf(f1.w);
    *(uint4*)(dst + i) = *(const uint4*)o;
  }
}

__global__ void cvt3_f32_bf16(const float* __restrict__ s0, const float* __restrict__ s1,
                              const float* __restrict__ s2, uint16_t* __restrict__ d0,
                              uint16_t* __restrict__ d1, uint16_t* __restrict__ d2, int n) {
  const float* src = (blockIdx.y == 0) ? s0 : (blockIdx.y == 1) ? s1 : s2;
  uint16_t* dst = (blockIdx.y == 0) ? d0 : (blockIdx.y == 1) ? d1 : d2;
  int i = (blockIdx.x * blockDim.x + threadIdx.x) * 8;
  const int stride = gridDim.x * blockDim.x * 8;
  for (; i < n; i += stride) {
    float4 f0 = *(const float4*)(src + i);
    float4 f1 = *(const float4*)(src + i + 4);
    alignas(16) uint16_t o[8];
    o[0] = f2bf(f0.x); o[1] = f2bf(f0.y); o[2] = f2bf(f0.z); o[3] = f2bf(f0.w);
    o[4] = f2bf(f1.x); o[5] = f2bf(f1.y); o[6] = f2bf(f1.z); o[7] = f2bf(f1.w);
    *(uint4*)(dst + i) = *(const uint4*)o;
  }
}

// ---------------------------------------------------------------------------
// NT GEMM, 256x256 tile, BK=64, 8 waves (2Mx4N), 4-phase/K-tile schedule with
// counted vmcnt(6) (T3+T4), st-style XOR LDS swizzle (T2), setprio (T5).
// LDS: A/B double-buffered, 128 KiB total, 1 block/CU.
//
// Swizzle (rule #21, both-sides-or-neither): LDS dest linear; global source
// pre-swizzled per-lane granule (l&7)^(l>>3); ds_read applies g^(row&7).
// A wave's 16 frag-rows then hit 8 distinct banks (2-way = free).
//
// Staging pipeline (per wave, 2 loads per half-tile, 8 per K-tile):
//   tile t phases stage: ph1 -> (t+1).A1 ; ph3 -> (t+2).B0,B1 ; ph4 -> (t+2).A0
//   (t+2) stages go into the CURRENT buffer's just-consumed regions:
//   B fully read by ph2-end barrier, A rows wr*128..+127 by ph3-end barrier.
//   Boundary: vmcnt(6) leaves exactly (t+2).B0,B1,A0 in flight; guarantees
//   ALL of tile t+1 arrived (own loads) + barrier (others'). Tail: vmcnt(0).
//
// MODE 0: merged QKV projection, B=[Wq;Wk;Wv] (3072x1024); epilogue bias +
//         Q/K/Vt(scattered transpose) select by n0>>10.
// MODE 2: scores = Q Kt / 32 per batch (grid.z), skip tiles tn>tm (causal).
// MODE 3: PV per batch, kmax = (tm+1)*256 causal, fp32 out.
// ---------------------------------------------------------------------------
template <int MODE>
__launch_bounds__(512, 2)
__global__ void gemm_bt(const uint16_t* __restrict__ Aroot,
                        const uint16_t* __restrict__ Broot,
                        const float* __restrict__ bq,
                        const float* __restrict__ bk,
                        const float* __restrict__ bv,
                        void* __restrict__ out0,
                        uint16_t* __restrict__ out1,
                        uint16_t* __restrict__ out2) {
  constexpr int K   = (MODE == 3) ? 2048 : 1024;
  constexpr int LDA = (MODE == 3) ? 2048 : 1024;
  constexpr int LDB = (MODE == 3) ? 2048 : 1024;

  const int tm = blockIdx.x, tn = blockIdx.y;
  if constexpr (MODE == 2) { if (tn > tm) return; }

  const uint16_t* A  = Aroot;
  const uint16_t* Bp = Broot;
  uint16_t* C16 = (uint16_t*)out0;
  float*    C32 = (float*)out0;
  if constexpr (MODE == 2) {
    size_t z = blockIdx.z;
    A   += z * (size_t)(SS * DD);
    Bp  += z * (size_t)(SS * DD);
    C16 += z * (size_t)SS * (size_t)SS;
  }
  if constexpr (MODE == 3) {
    size_t z = blockIdx.z;
    A   += z * (size_t)SS * (size_t)SS;
    Bp  += z * (size_t)(HH * SS);
    C32 += z * (size_t)(SS * HH);
  }

  const int m0 = tm * 256, n0 = tn * 256;
  int NT = K >> 6;
  if constexpr (MODE == 3) {
    int km = (tm + 1) * 256; if (km > K) km = K;
    NT = km >> 6;                       // 4..32
  }

  __shared__ uint16_t Al[2][256 * 64];  // 64 KiB
  __shared__ uint16_t Bl[2][256 * 64];  // 64 KiB

  const int tid  = threadIdx.x;
  const int lane = tid & 63;
  const int wv   = tid >> 6;            // 0..7
  const int wr   = wv >> 2;             // 0..1  wave m-row
  const int wc   = wv & 3;              // 0..3  wave n-col

  // ---- staging: per-lane pre-swizzled global source offset ----
  // one global_load_lds covers 8 rows x 128B; lane l -> phys granule l&7 of
  // row l>>3, loads LOGICAL granule (l&7)^(l>>3)  => LDS phys g holds logical
  // g^(row&7).
  const int sr = lane >> 3;
  const int sg = (lane & 7) ^ sr;
  const uint16_t* gAs = A  + (size_t)m0 * LDA + (size_t)sr * LDA + sg * 8;
  const uint16_t* gBs = Bp + (size_t)n0 * LDB + (size_t)sr * LDB + sg * 8;

#define STAGE_A(BUF, H, K0)                                                    \
  do {                                                                         \
    __builtin_amdgcn_global_load_lds(                                          \
        AS1C(gAs + (size_t)((H) * 128 + wv * 8) * LDA + (K0)),                 \
        AS3(&Al[BUF][((H) * 128 + wv * 8) * 64]), 16, 0, 0);                   \
    __builtin_amdgcn_global_load_lds(                                          \
        AS1C(gAs + (size_t)((H) * 128 + 64 + wv * 8) * LDA + (K0)),            \
        AS3(&Al[BUF][((H) * 128 + 64 + wv * 8) * 64]), 16, 0, 0);              \
  } while (0)

#define STAGE_B(BUF, H, K0)                                                    \
  do {                                                                         \
    __builtin_amdgcn_global_load_lds(                                          \
        AS1C(gBs + (size_t)((H) * 128 + wv * 8) * LDB + (K0)),                 \
        AS3(&Bl[BUF][((H) * 128 + wv * 8) * 64]), 16, 0, 0);                   \
    __builtin_amdgcn_global_load_lds(                                          \
        AS1C(gBs + (size_t)((H) * 128 + 64 + wv * 8) * LDB + (K0)),            \
        AS3(&Bl[BUF][((H) * 128 + 64 + wv * 8) * 64]), 16, 0, 0);              \
  } while (0)

  // ---- fragment ds_read offsets (swizzled) ----
  // frag row = base + (lane&15) (base mult of 16 -> row&7 == lane&7)
  // logical granule = kk*4 + (lane>>4) -> phys = g ^ (lane&7)
  const int rA  = lane & 15;
  const int gk  = lane >> 4;                 // 0..3
  const int sw  = lane & 7;
  const int ck0 = ((gk) ^ sw) * 8;           // kk=0 col offset (elems)
  const int ck1 = ((4 + gk) ^ sw) * 8;       // kk=1
  const int aro = (wr * 128 + rA) * 64;      // + (mh*64 + i*16)*64
  const int bro = (wc * 64 + rA) * 64;       // + (j*16)*64

  f32x4 acc[8][4];
#pragma unroll
  for (int i = 0; i < 8; i++)
#pragma unroll
    for (int j = 0; j < 4; j++)
#pragma unroll
      for (int e = 0; e < 4; e++) acc[i][j][e] = 0.f;

  bf16x8 af[4][2], bfj[4][2];

#define LDF(BASE, OFF) __builtin_bit_cast(bf16x8, *(const uint4*)&(BASE)[OFF])

#define QUAD(MH, JH)                                                           \
  do {                                                                         \
    _Pragma("unroll") for (int i = 0; i < 4; ++i)                              \
    _Pragma("unroll") for (int j = 0; j < 2; ++j) {                            \
      acc[(MH)*4 + i][(JH)*2 + j] = __builtin_amdgcn_mfma_f32_16x16x32_bf16(   \
          af[i][0], bfj[(JH)*2 + j][0], acc[(MH)*4 + i][(JH)*2 + j], 0, 0, 0); \
      acc[(MH)*4 + i][(JH)*2 + j] = __builtin_amdgcn_mfma_f32_16x16x32_bf16(   \
          af[i][1], bfj[(JH)*2 + j][1], acc[(MH)*4 + i][(JH)*2 + j], 0, 0, 0); \
    }                                                                          \
  } while (0)

  // ---- prologue: tile0 full + tile1 {B0,B1,A0} -> vmcnt(6) keeps t1 in flight
  STAGE_A(0, 0, 0); STAGE_A(0, 1, 0);
  STAGE_B(0, 0, 0); STAGE_B(0, 1, 0);
  if (NT > 1) {
    STAGE_B(1, 0, 64); STAGE_B(1, 1, 64);
    STAGE_A(1, 0, 64);
    asm volatile("s_waitcnt vmcnt(6)" ::: "memory");
  } else {
    asm volatile("s_waitcnt vmcnt(0)" ::: "memory");
  }
  wgbar();

  for (int t = 0; t < NT; ++t) {
    const int c = t & 1;
    const uint16_t* Ab = Al[c];
    const uint16_t* Bb = Bl[c];
    const int kc = t * 64;

    // ---- phase 1: read A-mh0 + B j=0,1 ; stage (t+1).A1 ----
#pragma unroll
    for (int i = 0; i < 4; ++i) {
      af[i][0] = LDF(Ab, aro + (i * 16) * 64 + ck0);
      af[i][1] = LDF(Ab, aro + (i * 16) * 64 + ck1);
    }
#pragma unroll
    for (int j = 0; j < 2; ++j) {
      bfj[j][0] = LDF(Bb, bro + (j * 16) * 64 + ck0);
      bfj[j][1] = LDF(Bb, bro + (j * 16) * 64 + ck1);
    }
    if (t + 1 < NT) STAGE_A(c ^ 1, 1, kc + 64);
    wgbar();
    asm volatile("s_waitcnt lgkmcnt(0)" ::: "memory");
    __builtin_amdgcn_s_setprio(1);
    QUAD(0, 0);
    __builtin_amdgcn_s_setprio(0);
    wgbar();

    // ---- phase 2: read B j=2,3 ----
#pragma unroll
    for (int j = 2; j < 4; ++j) {
      bfj[j][0] = LDF(Bb, bro + (j * 16) * 64 + ck0);
      bfj[j][1] = LDF(Bb, bro + (j * 16) * 64 + ck1);
    }
    wgbar();
    asm volatile("s_waitcnt lgkmcnt(0)" ::: "memory");
    __builtin_amdgcn_s_setprio(1);
    QUAD(0, 1);
    __builtin_amdgcn_s_setprio(0);
    wgbar();  // <- all B(c) reads retired: B(c) region reusable

    // ---- phase 3: read A-mh1 ; stage (t+2).B0,B1 into consumed B(c) ----
#pragma unroll
    for (int i = 0; i < 4; ++i) {
      af[i][0] = LDF(Ab, aro + ((64 + i * 16)) * 64 + ck0);
      af[i][1] = LDF(Ab, aro + ((64 + i * 16)) * 64 + ck1);
    }
    if (t + 2 < NT) { STAGE_B(c, 0, kc + 128); STAGE_B(c, 1, kc + 128); }
    wgbar();
    asm volatile("s_waitcnt lgkmcnt(0)" ::: "memory");
    __builtin_amdgcn_s_setprio(1);
    QUAD(1, 0);
    __builtin_amdgcn_s_setprio(0);
    wgbar();  // <- all A(c) rows 0..127-per-wr reads retired

    // ---- phase 4: stage (t+2).A0 ; MFMA ; boundary counted vmcnt ----
    if (t + 2 < NT) STAGE_A(c, 0, kc + 128);
    wgbar();
    __builtin_amdgcn_s_setprio(1);
    QUAD(1, 1);
    __builtin_amdgcn_s_setprio(0);
    if (t + 2 < NT) {
      asm volatile("s_waitcnt vmcnt(6)" ::: "memory");  // t+1 fully arrived
    } else if (t + 1 < NT) {
      asm volatile("s_waitcnt vmcnt(0)" ::: "memory");  // tail drain
    }
    wgbar();
  }

  // epilogue: C/D mapping col = lane&15, row = (lane>>4)*4 + e  [m89/m91]
  const int cr = (lane >> 4) * 4;
  const int cc = lane & 15;

  if constexpr (MODE == 0) {
    const int sel   = n0 >> 10;            // 0=Q, 1=K, 2=V (block-uniform)
    const int nloc0 = n0 & 1023;
    const float* __restrict__ bsel = (sel == 0) ? bq : (sel == 1) ? bk : bv;
    uint16_t* __restrict__ oQK = (sel == 1) ? out1 : (uint16_t*)out0;
#pragma unroll
    for (int i = 0; i < 8; i++) {
#pragma unroll
      for (int j = 0; j < 4; j++) {
        const int row0 = m0 + wr * 128 + i * 16 + cr;
        const int coll = nloc0 + wc * 64 + j * 16 + cc;
        const float badd = bsel[coll];
#pragma unroll
        for (int e = 0; e < 4; e++) {
          const float x = acc[i][j][e] + badd;
          const int r = row0 + e;
          if (sel == 2) {
            const int bz = r >> 11;
            const int s  = r & (SS - 1);
            out2[(size_t)bz * (HH * SS) + (size_t)coll * SS + s] = f2bf(x);
          } else {
            oQK[(size_t)r * HH + coll] = f2bf(x);
          }
        }
      }
    }
  } else {
#pragma unroll
    for (int i = 0; i < 8; i++) {
#pragma unroll
      for (int j = 0; j < 4; j++) {
        const int row0 = m0 + wr * 128 + i * 16 + cr;
        const int col  = n0 + wc * 64 + j * 16 + cc;
#pragma unroll
        for (int e = 0; e < 4; e++) {
          float x = acc[i][j][e];
          const int r = row0 + e;
          if constexpr (MODE == 2) {
            C16[(size_t)r * SS + col] = f2bf(x * 0.03125f);  // 1/sqrt(1024)
          } else {
            C32[(size_t)r * HH + col] = x;                   // fp32 final out
          }
        }
      }
    }
  }
#undef STAGE_A
#undef STAGE_B
#undef LDF
#undef QUAD
}

// one block (256 threads) per row; each thread owns 8 contiguous columns.
__launch_bounds__(256)
__global__ void softmax_causal(uint16_t* __restrict__ Sb) {
  const int rgl = blockIdx.x;          // 0..B*S-1
  const int b = rgl >> 11;
  const int i = rgl & (SS - 1);
  uint16_t* row = Sb + (size_t)b * SS * SS + (size_t)i * SS;
  const int t = threadIdx.x;
  const int base = t * 8;

  uint4 u = *(const uint4*)(row + base);
  const uint16_t* hs = (const uint16_t*)&u;
  float x[8];
  float lmax = -3.0e38f;
#pragma unroll
  for (int e = 0; e < 8; e++) {
    float f = bf2f(hs[e]);
    x[e] = (base + e <= i) ? f : -3.0e38f;
    lmax = fmaxf(lmax, x[e]);
  }
#pragma unroll
  for (int off = 32; off > 0; off >>= 1)
    lmax = fmaxf(lmax, __shfl_down(lmax, off));

  __shared__ float red[8];
  if ((t & 63) == 0) red[t >> 6] = lmax;
  __syncthreads();
  const float m = fmaxf(fmaxf(red[0], red[1]), fmaxf(red[2], red[3]));

  float lsum = 0.f;
#pragma unroll
  for (int e = 0; e < 8; e++) {
    float p = (base + e <= i) ? __expf(x[e] - m) : 0.f;
    x[e] = p;
    lsum += p;
  }
#pragma unroll
  for (int off = 32; off > 0; off >>= 1) lsum += __shfl_down(lsum, off);
  if ((t & 63) == 0) red[4 + (t >> 6)] = lsum;
  __syncthreads();
  const float inv = 1.f / (red[4] + red[5] + red[6] + red[7]);

  alignas(16) uint16_t o[8];
#pragma unroll
  for (int e = 0; e < 8; e++) o[e] = f2bf(x[e] * inv);
  *(uint4*)(row + base) = *(const uint4*)o;
}

extern "C" void kernel_launch(void* const* d_in, const int* in_sizes, int n_in,
                              void* d_out, int out_size, void* d_ws, size_t ws_size,
                              hipStream_t stream) {
  const float* x  = (const float*)d_in[0];
  const float* Wq = (const float*)d_in[1];
  const float* bq = (const float*)d_in[2];
  const float* Wk = (const float*)d_in[3];
  const float* bk = (const float*)d_in[4];
  const float* Wv = (const float*)d_in[5];
  const float* bv = (const float*)d_in[6];

  uint16_t* ws = (uint16_t*)d_ws;
  const size_t QKV = (size_t)BB * SS * HH;  // 16,777,216 elems = 32 MB bf16
  uint16_t* Q  = ws;
  uint16_t* Kp = ws + QKV;
  uint16_t* Vt = ws + 2 * QKV;
  uint16_t* Sb = ws + 3 * QKV;              // 8*2048*2048 bf16 = 64 MB
  uint16_t* xb  = Sb;                       // aliases Sb (dead before MODE 2)
  uint16_t* Wqb = Sb + QKV;
  uint16_t* Wkb = Wqb + (size_t)HH * DD;
  uint16_t* Wvb = Wkb + (size_t)HH * DD;

  dim3 blk(256);
  dim3 blk512(512);
  const int nx = BB * SS * DD;              // 16,777,216
  const int nw = HH * DD;                   // 1,048,576
  cvt_f32_bf16<<<dim3(nx / 2048), blk, 0, stream>>>(x, xb, nx);
  cvt3_f32_bf16<<<dim3(nw / 2048, 3), blk, 0, stream>>>(Wq, Wk, Wv, Wqb, Wkb, Wvb, nw);

  // merged QKV projection: M=16384, N=3072 -> 64 x 12 blocks of 256^2
  gemm_bt<0><<<dim3(BB * SS / 256, 3 * HH / 256), blk512, 0, stream>>>(
      xb, Wqb, bq, bk, bv, Q, Kp, Vt);
  gemm_bt<2><<<dim3(SS / 256, SS / 256, BB), blk512, 0, stream>>>(
      Q, Kp, nullptr, nullptr, nullptr, Sb, nullptr, nullptr);
  softmax_causal<<<dim3(BB * SS), blk, 0, stream>>>(Sb);
  gemm_bt<3><<<dim3(SS / 256, HH / 256, BB), blk512, 0, stream>>>(
      Sb, Vt, nullptr, nullptr, nullptr, d_out, nullptr, nullptr);
}

// Round 3
// 435.740 us; speedup vs baseline: 1.0042x; 1.0042x over previous
//
#include <hip/hip_runtime.h>
#include <hip/hip_bf16.h>
#include <cstdint>

#define BB 8
#define SS 2048
#define DD 1024
#define HH 1024

typedef __bf16 bf16x8 __attribute__((ext_vector_type(8)));
typedef float f32x4 __attribute__((ext_vector_type(4)));

// address-space casts for global_load_lds (direct global->LDS DMA)
#define AS1C(p) ((const __attribute__((address_space(1))) void*)(p))
#define AS3(p)  ((__attribute__((address_space(3))) void*)(p))

__device__ __forceinline__ float bf2f(uint16_t h) {
  union { uint32_t u; float f; } v; v.u = ((uint32_t)h) << 16; return v.f;
}
__device__ __forceinline__ uint16_t f2bf(float f) {
  union { float f; uint32_t u; } v; v.f = f;
  uint32_t u = v.u;
  return (uint16_t)((u + 0x7FFFu + ((u >> 16) & 1u)) >> 16);
}

// raw workgroup barrier WITHOUT the vmcnt(0) drain __syncthreads() emits.
__device__ __forceinline__ void wgbar() {
  asm volatile("" ::: "memory");
  __builtin_amdgcn_s_barrier();
  asm volatile("" ::: "memory");
}

// fp32 -> bf16 (RNE), vectorized 8 elems/thread, grid-stride. n % 8 == 0.
__global__ void cvt_f32_bf16(const float* __restrict__ src,
                             uint16_t* __restrict__ dst, int n) {
  int i = (blockIdx.x * blockDim.x + threadIdx.x) * 8;
  const int stride = gridDim.x * blockDim.x * 8;
  for (; i < n; i += stride) {
    float4 f0 = *(const float4*)(src + i);
    float4 f1 = *(const float4*)(src + i + 4);
    alignas(16) uint16_t o[8];
    o[0] = f2bf(f0.x); o[1] = f2bf(f0.y); o[2] = f2bf(f0.z); o[3] = f2bf(f0.w);
    o[4] = f2bf(f1.x); o[5] = f2bf(f1.y); o[6] = f2bf(f1.z); o[7] = f2bf(f1.w);
    *(uint4*)(dst + i) = *(const uint4*)o;
  }
}

__global__ void cvt3_f32_bf16(const float* __restrict__ s0, const float* __restrict__ s1,
                              const float* __restrict__ s2, uint16_t* __restrict__ d0,
                              uint16_t* __restrict__ d1, uint16_t* __restrict__ d2, int n) {
  const float* src = (blockIdx.y == 0) ? s0 : (blockIdx.y == 1) ? s1 : s2;
  uint16_t* dst = (blockIdx.y == 0) ? d0 : (blockIdx.y == 1) ? d1 : d2;
  int i = (blockIdx.x * blockDim.x + threadIdx.x) * 8;
  const int stride = gridDim.x * blockDim.x * 8;
  for (; i < n; i += stride) {
    float4 f0 = *(const float4*)(src + i);
    float4 f1 = *(const float4*)(src + i + 4);
    alignas(16) uint16_t o[8];
    o[0] = f2bf(f0.x); o[1] = f2bf(f0.y); o[2] = f2bf(f0.z); o[3] = f2bf(f0.w);
    o[4] = f2bf(f1.x); o[5] = f2bf(f1.y); o[6] = f2bf(f1.z); o[7] = f2bf(f1.w);
    *(uint4*)(dst + i) = *(const uint4*)o;
  }
}

// ---------------------------------------------------------------------------
// NT GEMM, 256x256 tile, BK=64, 8 waves (2Mx4N), 4-phase/K-tile schedule with
// counted vmcnt(6) (T3+T4), XOR LDS swizzle (T2), setprio (T5).
// ROUND-3 FIX (rule #18): sched_barrier(0) after every inline-asm lgkmcnt
// wait and around each MFMA cluster — without these, hipcc drags the
// register-only MFMAs across the asm waits/barriers and the phase schedule
// degenerates (r2: MfmaUtil 27%, dur 154.9us despite 0 bank conflicts).
//
// Swizzle: LDS dest linear; global source pre-swizzled per-lane granule
// (l&7)^(l>>3); ds_read applies g^(row&7). Verified: SQ_LDS_BANK_CONFLICT=0.
//
// Staging pipeline (per wave, 2 loads per half-tile, 8 per K-tile):
//   tile t: ph1 -> (t+1).A1 ; ph3 -> (t+2).B0,B1 ; ph4 -> (t+2).A0
//   Boundary: vmcnt(6) retires exactly tile t+1's 8 loads. Tail: vmcnt(0).
//
// MODE 0: merged QKV projection. MODE 2: scores (causal skip). MODE 3: PV.
// ---------------------------------------------------------------------------
template <int MODE>
__launch_bounds__(512, 2)
__global__ void gemm_bt(const uint16_t* __restrict__ Aroot,
                        const uint16_t* __restrict__ Broot,
                        const float* __restrict__ bq,
                        const float* __restrict__ bk,
                        const float* __restrict__ bv,
                        void* __restrict__ out0,
                        uint16_t* __restrict__ out1,
                        uint16_t* __restrict__ out2) {
  constexpr int K   = (MODE == 3) ? 2048 : 1024;
  constexpr int LDA = (MODE == 3) ? 2048 : 1024;
  constexpr int LDB = (MODE == 3) ? 2048 : 1024;

  const int tm = blockIdx.x, tn = blockIdx.y;
  if constexpr (MODE == 2) { if (tn > tm) return; }

  const uint16_t* A  = Aroot;
  const uint16_t* Bp = Broot;
  uint16_t* C16 = (uint16_t*)out0;
  float*    C32 = (float*)out0;
  if constexpr (MODE == 2) {
    size_t z = blockIdx.z;
    A   += z * (size_t)(SS * DD);
    Bp  += z * (size_t)(SS * DD);
    C16 += z * (size_t)SS * (size_t)SS;
  }
  if constexpr (MODE == 3) {
    size_t z = blockIdx.z;
    A   += z * (size_t)SS * (size_t)SS;
    Bp  += z * (size_t)(HH * SS);
    C32 += z * (size_t)(SS * HH);
  }

  const int m0 = tm * 256, n0 = tn * 256;
  int NT = K >> 6;
  if constexpr (MODE == 3) {
    int km = (tm + 1) * 256; if (km > K) km = K;
    NT = km >> 6;                       // 4..32
  }

  __shared__ uint16_t Al[2][256 * 64];  // 64 KiB
  __shared__ uint16_t Bl[2][256 * 64];  // 64 KiB

  const int tid  = threadIdx.x;
  const int lane = tid & 63;
  const int wv   = tid >> 6;            // 0..7
  const int wr   = wv >> 2;             // 0..1  wave m-row
  const int wc   = wv & 3;              // 0..3  wave n-col

  // ---- staging: per-lane pre-swizzled global source offset ----
  const int sr = lane >> 3;
  const int sg = (lane & 7) ^ sr;
  const uint16_t* gAs = A  + (size_t)m0 * LDA + (size_t)sr * LDA + sg * 8;
  const uint16_t* gBs = Bp + (size_t)n0 * LDB + (size_t)sr * LDB + sg * 8;

#define STAGE_A(BUF, H, K0)                                                    \
  do {                                                                         \
    __builtin_amdgcn_global_load_lds(                                          \
        AS1C(gAs + (size_t)((H) * 128 + wv * 8) * LDA + (K0)),                 \
        AS3(&Al[BUF][((H) * 128 + wv * 8) * 64]), 16, 0, 0);                   \
    __builtin_amdgcn_global_load_lds(                                          \
        AS1C(gAs + (size_t)((H) * 128 + 64 + wv * 8) * LDA + (K0)),            \
        AS3(&Al[BUF][((H) * 128 + 64 + wv * 8) * 64]), 16, 0, 0);              \
  } while (0)

#define STAGE_B(BUF, H, K0)                                                    \
  do {                                                                         \
    __builtin_amdgcn_global_load_lds(                                          \
        AS1C(gBs + (size_t)((H) * 128 + wv * 8) * LDB + (K0)),                 \
        AS3(&Bl[BUF][((H) * 128 + wv * 8) * 64]), 16, 0, 0);                   \
    __builtin_amdgcn_global_load_lds(                                          \
        AS1C(gBs + (size_t)((H) * 128 + 64 + wv * 8) * LDB + (K0)),            \
        AS3(&Bl[BUF][((H) * 128 + 64 + wv * 8) * 64]), 16, 0, 0);              \
  } while (0)

  // ---- fragment ds_read offsets (swizzled) ----
  const int rA  = lane & 15;
  const int gk  = lane >> 4;                 // 0..3
  const int sw  = lane & 7;
  const int ck0 = ((gk) ^ sw) * 8;           // kk=0 col offset (elems)
  const int ck1 = ((4 + gk) ^ sw) * 8;       // kk=1
  const int aro = (wr * 128 + rA) * 64;      // + (mh*64 + i*16)*64
  const int bro = (wc * 64 + rA) * 64;       // + (j*16)*64

  f32x4 acc[8][4];
#pragma unroll
  for (int i = 0; i < 8; i++)
#pragma unroll
    for (int j = 0; j < 4; j++)
#pragma unroll
      for (int e = 0; e < 4; e++) acc[i][j][e] = 0.f;

  bf16x8 af[4][2], bfj[4][2];

#define LDF(BASE, OFF) __builtin_bit_cast(bf16x8, *(const uint4*)&(BASE)[OFF])

#define QUAD(MH, JH)                                                           \
  do {                                                                         \
    _Pragma("unroll") for (int i = 0; i < 4; ++i)                              \
    _Pragma("unroll") for (int j = 0; j < 2; ++j) {                            \
      acc[(MH)*4 + i][(JH)*2 + j] = __builtin_amdgcn_mfma_f32_16x16x32_bf16(   \
          af[i][0], bfj[(JH)*2 + j][0], acc[(MH)*4 + i][(JH)*2 + j], 0, 0, 0); \
      acc[(MH)*4 + i][(JH)*2 + j] = __builtin_amdgcn_mfma_f32_16x16x32_bf16(   \
          af[i][1], bfj[(JH)*2 + j][1], acc[(MH)*4 + i][(JH)*2 + j], 0, 0, 0); \
    }                                                                          \
  } while (0)

// pinned MFMA cluster: nothing crosses in or out (rule #18)
#define MFMA_CLUSTER(MH, JH)                                                   \
  do {                                                                         \
    __builtin_amdgcn_sched_barrier(0);                                         \
    __builtin_amdgcn_s_setprio(1);                                             \
    QUAD(MH, JH);                                                              \
    __builtin_amdgcn_s_setprio(0);                                             \
    __builtin_amdgcn_sched_barrier(0);                                         \
  } while (0)

  // ---- prologue: tile0 full + tile1 {B0,B1,A0} -> vmcnt(6) keeps t1 in flight
  STAGE_A(0, 0, 0); STAGE_A(0, 1, 0);
  STAGE_B(0, 0, 0); STAGE_B(0, 1, 0);
  if (NT > 1) {
    STAGE_B(1, 0, 64); STAGE_B(1, 1, 64);
    STAGE_A(1, 0, 64);
    asm volatile("s_waitcnt vmcnt(6)" ::: "memory");
  } else {
    asm volatile("s_waitcnt vmcnt(0)" ::: "memory");
  }
  wgbar();

  for (int t = 0; t < NT; ++t) {
    const int c = t & 1;
    const uint16_t* Ab = Al[c];
    const uint16_t* Bb = Bl[c];
    const int kc = t * 64;

    // ---- phase 1: read A-mh0 + B j=0,1 ; stage (t+1).A1 ----
#pragma unroll
    for (int i = 0; i < 4; ++i) {
      af[i][0] = LDF(Ab, aro + (i * 16) * 64 + ck0);
      af[i][1] = LDF(Ab, aro + (i * 16) * 64 + ck1);
    }
#pragma unroll
    for (int j = 0; j < 2; ++j) {
      bfj[j][0] = LDF(Bb, bro + (j * 16) * 64 + ck0);
      bfj[j][1] = LDF(Bb, bro + (j * 16) * 64 + ck1);
    }
    if (t + 1 < NT) STAGE_A(c ^ 1, 1, kc + 64);
    asm volatile("s_waitcnt lgkmcnt(8)" ::: "memory");  // throttle: 12 issued
    wgbar();
    asm volatile("s_waitcnt lgkmcnt(0)" ::: "memory");
    __builtin_amdgcn_sched_barrier(0);
    MFMA_CLUSTER(0, 0);
    wgbar();

    // ---- phase 2: read B j=2,3 ----
#pragma unroll
    for (int j = 2; j < 4; ++j) {
      bfj[j][0] = LDF(Bb, bro + (j * 16) * 64 + ck0);
      bfj[j][1] = LDF(Bb, bro + (j * 16) * 64 + ck1);
    }
    wgbar();
    asm volatile("s_waitcnt lgkmcnt(0)" ::: "memory");
    __builtin_amdgcn_sched_barrier(0);
    MFMA_CLUSTER(0, 1);
    wgbar();  // <- all B(c) reads retired: B(c) region reusable

    // ---- phase 3: read A-mh1 ; stage (t+2).B0,B1 into consumed B(c) ----
#pragma unroll
    for (int i = 0; i < 4; ++i) {
      af[i][0] = LDF(Ab, aro + ((64 + i * 16)) * 64 + ck0);
      af[i][1] = LDF(Ab, aro + ((64 + i * 16)) * 64 + ck1);
    }
    if (t + 2 < NT) { STAGE_B(c, 0, kc + 128); STAGE_B(c, 1, kc + 128); }
    wgbar();
    asm volatile("s_waitcnt lgkmcnt(0)" ::: "memory");
    __builtin_amdgcn_sched_barrier(0);
    MFMA_CLUSTER(1, 0);
    wgbar();  // <- all A(c) reads retired

    // ---- phase 4: stage (t+2).A0 ; MFMA ; boundary counted vmcnt ----
    if (t + 2 < NT) STAGE_A(c, 0, kc + 128);
    wgbar();
    MFMA_CLUSTER(1, 1);
    if (t + 2 < NT) {
      asm volatile("s_waitcnt vmcnt(6)" ::: "memory");  // t+1 fully arrived
    } else if (t + 1 < NT) {
      asm volatile("s_waitcnt vmcnt(0)" ::: "memory");  // tail drain
    }
    wgbar();
  }

  // epilogue: C/D mapping col = lane&15, row = (lane>>4)*4 + e  [m89/m91]
  const int cr = (lane >> 4) * 4;
  const int cc = lane & 15;

  if constexpr (MODE == 0) {
    const int sel   = n0 >> 10;            // 0=Q, 1=K, 2=V (block-uniform)
    const int nloc0 = n0 & 1023;
    const float* __restrict__ bsel = (sel == 0) ? bq : (sel == 1) ? bk : bv;
    uint16_t* __restrict__ oQK = (sel == 1) ? out1 : (uint16_t*)out0;
#pragma unroll
    for (int i = 0; i < 8; i++) {
#pragma unroll
      for (int j = 0; j < 4; j++) {
        const int row0 = m0 + wr * 128 + i * 16 + cr;
        const int coll = nloc0 + wc * 64 + j * 16 + cc;
        const float badd = bsel[coll];
#pragma unroll
        for (int e = 0; e < 4; e++) {
          const float x = acc[i][j][e] + badd;
          const int r = row0 + e;
          if (sel == 2) {
            const int bz = r >> 11;
            const int s  = r & (SS - 1);
            out2[(size_t)bz * (HH * SS) + (size_t)coll * SS + s] = f2bf(x);
          } else {
            oQK[(size_t)r * HH + coll] = f2bf(x);
          }
        }
      }
    }
  } else {
#pragma unroll
    for (int i = 0; i < 8; i++) {
#pragma unroll
      for (int j = 0; j < 4; j++) {
        const int row0 = m0 + wr * 128 + i * 16 + cr;
        const int col  = n0 + wc * 64 + j * 16 + cc;
#pragma unroll
        for (int e = 0; e < 4; e++) {
          float x = acc[i][j][e];
          const int r = row0 + e;
          if constexpr (MODE == 2) {
            C16[(size_t)r * SS + col] = f2bf(x * 0.03125f);  // 1/sqrt(1024)
          } else {
            C32[(size_t)r * HH + col] = x;                   // fp32 final out
          }
        }
      }
    }
  }
#undef STAGE_A
#undef STAGE_B
#undef LDF
#undef QUAD
#undef MFMA_CLUSTER
}

// one block (256 threads) per row; each thread owns 8 contiguous columns.
__launch_bounds__(256)
__global__ void softmax_causal(uint16_t* __restrict__ Sb) {
  const int rgl = blockIdx.x;          // 0..B*S-1
  const int b = rgl >> 11;
  const int i = rgl & (SS - 1);
  uint16_t* row = Sb + (size_t)b * SS * SS + (size_t)i * SS;
  const int t = threadIdx.x;
  const int base = t * 8;

  uint4 u = *(const uint4*)(row + base);
  const uint16_t* hs = (const uint16_t*)&u;
  float x[8];
  float lmax = -3.0e38f;
#pragma unroll
  for (int e = 0; e < 8; e++) {
    float f = bf2f(hs[e]);
    x[e] = (base + e <= i) ? f : -3.0e38f;
    lmax = fmaxf(lmax, x[e]);
  }
#pragma unroll
  for (int off = 32; off > 0; off >>= 1)
    lmax = fmaxf(lmax, __shfl_down(lmax, off));

  __shared__ float red[8];
  if ((t & 63) == 0) red[t >> 6] = lmax;
  __syncthreads();
  const float m = fmaxf(fmaxf(red[0], red[1]), fmaxf(red[2], red[3]));

  float lsum = 0.f;
#pragma unroll
  for (int e = 0; e < 8; e++) {
    float p = (base + e <= i) ? __expf(x[e] - m) : 0.f;
    x[e] = p;
    lsum += p;
  }
#pragma unroll
  for (int off = 32; off > 0; off >>= 1) lsum += __shfl_down(lsum, off);
  if ((t & 63) == 0) red[4 + (t >> 6)] = lsum;
  __syncthreads();
  const float inv = 1.f / (red[4] + red[5] + red[6] + red[7]);

  alignas(16) uint16_t o[8];
#pragma unroll
  for (int e = 0; e < 8; e++) o[e] = f2bf(x[e] * inv);
  *(uint4*)(row + base) = *(const uint4*)o;
}

extern "C" void kernel_launch(void* const* d_in, const int* in_sizes, int n_in,
                              void* d_out, int out_size, void* d_ws, size_t ws_size,
                              hipStream_t stream) {
  const float* x  = (const float*)d_in[0];
  const float* Wq = (const float*)d_in[1];
  const float* bq = (const float*)d_in[2];
  const float* Wk = (const float*)d_in[3];
  const float* bk = (const float*)d_in[4];
  const float* Wv = (const float*)d_in[5];
  const float* bv = (const float*)d_in[6];

  uint16_t* ws = (uint16_t*)d_ws;
  const size_t QKV = (size_t)BB * SS * HH;  // 16,777,216 elems = 32 MB bf16
  uint16_t* Q  = ws;
  uint16_t* Kp = ws + QKV;
  uint16_t* Vt = ws + 2 * QKV;
  uint16_t* Sb = ws + 3 * QKV;              // 8*2048*2048 bf16 = 64 MB
  uint16_t* xb  = Sb;                       // aliases Sb (dead before MODE 2)
  uint16_t* Wqb = Sb + QKV;
  uint16_t* Wkb = Wqb + (size_t)HH * DD;
  uint16_t* Wvb = Wkb + (size_t)HH * DD;

  dim3 blk(256);
  dim3 blk512(512);
  const int nx = BB * SS * DD;              // 16,777,216
  const int nw = HH * DD;                   // 1,048,576
  cvt_f32_bf16<<<dim3(nx / 2048), blk, 0, stream>>>(x, xb, nx);
  cvt3_f32_bf16<<<dim3(nw / 2048, 3), blk, 0, stream>>>(Wq, Wk, Wv, Wqb, Wkb, Wvb, nw);

  // merged QKV projection: M=16384, N=3072 -> 64 x 12 blocks of 256^2
  gemm_bt<0><<<dim3(BB * SS / 256, 3 * HH / 256), blk512, 0, stream>>>(
      xb, Wqb, bq, bk, bv, Q, Kp, Vt);
  gemm_bt<2><<<dim3(SS / 256, SS / 256, BB), blk512, 0, stream>>>(
      Q, Kp, nullptr, nullptr, nullptr, Sb, nullptr, nullptr);
  softmax_causal<<<dim3(BB * SS), blk, 0, stream>>>(Sb);
  gemm_bt<3><<<dim3(SS / 256, HH / 256, BB), blk512, 0, stream>>>(
      Sb, Vt, nullptr, nullptr, nullptr, d_out, nullptr, nullptr);
}

// Round 4
// 435.049 us; speedup vs baseline: 1.0058x; 1.0016x over previous
//
#include <hip/hip_runtime.h>
#include <hip/hip_bf16.h>
#include <cstdint>

#define BB 8
#define SS 2048
#define DD 1024
#define HH 1024

typedef __bf16 bf16x8 __attribute__((ext_vector_type(8)));
typedef float f32x4 __attribute__((ext_vector_type(4)));

// address-space casts for global_load_lds (direct global->LDS DMA)
#define AS1C(p) ((const __attribute__((address_space(1))) void*)(p))
#define AS3(p)  ((__attribute__((address_space(3))) void*)(p))

__device__ __forceinline__ float bf2f(uint16_t h) {
  union { uint32_t u; float f; } v; v.u = ((uint32_t)h) << 16; return v.f;
}
__device__ __forceinline__ uint16_t f2bf(float f) {
  union { float f; uint32_t u; } v; v.f = f;
  uint32_t u = v.u;
  return (uint16_t)((u + 0x7FFFu + ((u >> 16) & 1u)) >> 16);
}

// fp32 -> bf16 (RNE), vectorized 8 elems/thread, grid-stride. n % 8 == 0.
__global__ void cvt_f32_bf16(const float* __restrict__ src,
                             uint16_t* __restrict__ dst, int n) {
  int i = (blockIdx.x * blockDim.x + threadIdx.x) * 8;
  const int stride = gridDim.x * blockDim.x * 8;
  for (; i < n; i += stride) {
    float4 f0 = *(const float4*)(src + i);
    float4 f1 = *(const float4*)(src + i + 4);
    alignas(16) uint16_t o[8];
    o[0] = f2bf(f0.x); o[1] = f2bf(f0.y); o[2] = f2bf(f0.z); o[3] = f2bf(f0.w);
    o[4] = f2bf(f1.x); o[5] = f2bf(f1.y); o[6] = f2bf(f1.z); o[7] = f2bf(f1.w);
    *(uint4*)(dst + i) = *(const uint4*)o;
  }
}

// three same-size fp32->bf16 converts in one dispatch (blockIdx.y selects)
__global__ void cvt3_f32_bf16(const float* __restrict__ s0, const float* __restrict__ s1,
                              const float* __restrict__ s2, uint16_t* __restrict__ d0,
                              uint16_t* __restrict__ d1, uint16_t* __restrict__ d2, int n) {
  const float* src = (blockIdx.y == 0) ? s0 : (blockIdx.y == 1) ? s1 : s2;
  uint16_t* dst = (blockIdx.y == 0) ? d0 : (blockIdx.y == 1) ? d1 : d2;
  int i = (blockIdx.x * blockDim.x + threadIdx.x) * 8;
  const int stride = gridDim.x * blockDim.x * 8;
  for (; i < n; i += stride) {
    float4 f0 = *(const float4*)(src + i);
    float4 f1 = *(const float4*)(src + i + 4);
    alignas(16) uint16_t o[8];
    o[0] = f2bf(f0.x); o[1] = f2bf(f0.y); o[2] = f2bf(f0.z); o[3] = f2bf(f0.w);
    o[4] = f2bf(f1.x); o[5] = f2bf(f1.y); o[6] = f2bf(f1.z); o[7] = f2bf(f1.w);
    *(uint4*)(dst + i) = *(const uint4*)o;
  }
}

// NT GEMM: C[m][n] = sum_k A[m][k] * B[n][k]  (bf16, K-contiguous operands)
// K-loop: BK=64 as two 32-wide LDS buffers (unroll x2) -> 2 barriers per
// 64 K-elems, 32 MFMA per vmcnt drain. Staging via global_load_lds w=16.
// [r4] GEMM core reverted verbatim to the 141.9us harness-verified r0
// structure (4-phase 256^2 experiments r2/r3 measured slower: 155/189us).
// [r4] MODE 0 only: T1 XCD-chunked blockIdx swizzle (tn-fastest within
// chunk) — each XCD keeps its 16 A-panels (4MB) L2-resident instead of all
// XCDs streaming all of A (r0 FETCH 143MB vs ~38MB ideal). Modes 2/3 keep
// the default round-robin: their causal work-imbalance would concentrate on
// high-tm XCDs under chunking (up to ~10x skew).
// MODE 0: merged QKV projection. B = [Wq;Wk;Wv] (3072x1024). Epilogue picks
//         Q / K / Vt(transposed) + bias by n0>>10 (block-uniform).
// MODE 2: scores = Q Kt / 32 per batch (grid.z). skip tiles tn>tm (causal).
// MODE 3: PV per batch (grid.z). kmax causal. fp32 output.
template <int MODE>
__launch_bounds__(256, 2)
__global__ void gemm_bt(const uint16_t* __restrict__ Aroot,
                        const uint16_t* __restrict__ Broot,
                        const float* __restrict__ bq,
                        const float* __restrict__ bk,
                        const float* __restrict__ bv,
                        void* __restrict__ out0,
                        uint16_t* __restrict__ out1,
                        uint16_t* __restrict__ out2) {
  constexpr int K   = (MODE == 3) ? 2048 : 1024;
  constexpr int LDA = (MODE == 3) ? 2048 : 1024;
  constexpr int LDB = (MODE == 3) ? 2048 : 1024;

  int tm, tn;
  if constexpr (MODE == 0) {
    // T1: invert the HW round-robin (bid%8 -> XCD) into contiguous chunks.
    // nwg = 128*24 = 3072, %8 == 0 -> bijective. tn-fastest decomposition:
    // chunk of 384 = 16 tm-rows x 24 tn -> per-XCD A working set 4MB (L2).
    const int gx = gridDim.x, gy = gridDim.y;
    const int bid = blockIdx.y * gx + blockIdx.x;
    const int chunk = (gx * gy) >> 3;
    const int nb = (bid & 7) * chunk + (bid >> 3);
    tm = nb / gy;
    tn = nb - tm * gy;
  } else {
    tm = blockIdx.x; tn = blockIdx.y;
  }
  if constexpr (MODE == 2) { if (tn > tm) return; }

  const uint16_t* A = Aroot;
  const uint16_t* Bp = Broot;
  uint16_t* C16 = (uint16_t*)out0;
  float*    C32 = (float*)out0;
  if constexpr (MODE == 2) {
    size_t z = blockIdx.z;
    A  += z * (size_t)(SS * DD);
    Bp += z * (size_t)(SS * DD);
    C16 += z * (size_t)SS * (size_t)SS;
  }
  if constexpr (MODE == 3) {
    size_t z = blockIdx.z;
    A  += z * (size_t)SS * (size_t)SS;
    Bp += z * (size_t)(HH * SS);
    C32 += z * (size_t)(SS * HH);
  }

  const int m0 = tm * 128, n0 = tn * 128;
  int kmax = K;
  if constexpr (MODE == 3) {
    kmax = (tm + 1) * 128;           // multiple of 128 -> multiple of 64
    if (kmax > K) kmax = K;
  }

  __shared__ uint16_t As0[128 * 32];
  __shared__ uint16_t As1[128 * 32];
  __shared__ uint16_t Bs0[128 * 32];
  __shared__ uint16_t Bs1[128 * 32];

  const int tid  = threadIdx.x;
  const int lane = tid & 63;
  const int wv   = tid >> 6;
  const int wm   = (wv & 1) * 64;   // wave's m offset within 128-tile
  const int wn   = (wv >> 1) * 64;  // wave's n offset

  f32x4 acc[4][4];
#pragma unroll
  for (int i = 0; i < 4; i++)
#pragma unroll
    for (int j = 0; j < 4; j++)
#pragma unroll
      for (int e = 0; e < 4; e++) acc[i][j][e] = 0.f;

  // global_load_lds lane mapping within a 16-row chunk:
  // lane l -> row l>>2, elem col (l&3)*8 (16B)
  const int lrow = lane >> 2;
  const int lcol = (lane & 3) * 8;
  const int r0   = wv * 32;         // this wave's 32-row slab

  const uint16_t* gA = A + (size_t)(m0 + r0 + lrow) * LDA + lcol;
  const uint16_t* gB = Bp + (size_t)(n0 + r0 + lrow) * LDB + lcol;

  // fragment indices (A and B operands share the same lane mapping)
  const int fr = lane & 15;
  const int fk = (lane >> 4) * 8;

  for (int k0 = 0; k0 < kmax; k0 += 64) {
    __syncthreads();  // prior ds_reads done before overwrite
    __builtin_amdgcn_global_load_lds(AS1C(gA + k0), AS3(&As0[r0 * 32]), 16, 0, 0);
    __builtin_amdgcn_global_load_lds(AS1C(gA + k0 + 16 * LDA), AS3(&As0[(r0 + 16) * 32]), 16, 0, 0);
    __builtin_amdgcn_global_load_lds(AS1C(gA + k0 + 32), AS3(&As1[r0 * 32]), 16, 0, 0);
    __builtin_amdgcn_global_load_lds(AS1C(gA + k0 + 32 + 16 * LDA), AS3(&As1[(r0 + 16) * 32]), 16, 0, 0);
    __builtin_amdgcn_global_load_lds(AS1C(gB + k0), AS3(&Bs0[r0 * 32]), 16, 0, 0);
    __builtin_amdgcn_global_load_lds(AS1C(gB + k0 + 16 * LDB), AS3(&Bs0[(r0 + 16) * 32]), 16, 0, 0);
    __builtin_amdgcn_global_load_lds(AS1C(gB + k0 + 32), AS3(&Bs1[r0 * 32]), 16, 0, 0);
    __builtin_amdgcn_global_load_lds(AS1C(gB + k0 + 32 + 16 * LDB), AS3(&Bs1[(r0 + 16) * 32]), 16, 0, 0);
    __syncthreads();  // drains vmcnt(0): both 32-chunks staged

    bf16x8 af[4], bfr[4];
#pragma unroll
    for (int i = 0; i < 4; i++)
      af[i] = __builtin_bit_cast(bf16x8, *(const uint4*)&As0[(wm + i * 16 + fr) * 32 + fk]);
#pragma unroll
    for (int j = 0; j < 4; j++)
      bfr[j] = __builtin_bit_cast(bf16x8, *(const uint4*)&Bs0[(wn + j * 16 + fr) * 32 + fk]);
#pragma unroll
    for (int i = 0; i < 4; i++)
#pragma unroll
      for (int j = 0; j < 4; j++)
        acc[i][j] = __builtin_amdgcn_mfma_f32_16x16x32_bf16(af[i], bfr[j], acc[i][j], 0, 0, 0);

#pragma unroll
    for (int i = 0; i < 4; i++)
      af[i] = __builtin_bit_cast(bf16x8, *(const uint4*)&As1[(wm + i * 16 + fr) * 32 + fk]);
#pragma unroll
    for (int j = 0; j < 4; j++)
      bfr[j] = __builtin_bit_cast(bf16x8, *(const uint4*)&Bs1[(wn + j * 16 + fr) * 32 + fk]);
#pragma unroll
    for (int i = 0; i < 4; i++)
#pragma unroll
      for (int j = 0; j < 4; j++)
        acc[i][j] = __builtin_amdgcn_mfma_f32_16x16x32_bf16(af[i], bfr[j], acc[i][j], 0, 0, 0);
  }

  // epilogue: C/D mapping col = lane&15, row = (lane>>4)*4 + e  [verified m89/m91]
  const int cr = (lane >> 4) * 4;
  const int cc = lane & 15;

  if constexpr (MODE == 0) {
    const int sel   = n0 >> 10;            // 0=Q, 1=K, 2=V (block-uniform)
    const int nloc0 = n0 & 1023;
    const float* __restrict__ bsel = (sel == 0) ? bq : (sel == 1) ? bk : bv;
    uint16_t* __restrict__ oQK = (sel == 1) ? out1 : (uint16_t*)out0;
#pragma unroll
    for (int i = 0; i < 4; i++) {
#pragma unroll
      for (int j = 0; j < 4; j++) {
        const int row0 = m0 + wm + i * 16 + cr;
        const int coll = nloc0 + wn + j * 16 + cc;
        const float badd = bsel[coll];
#pragma unroll
        for (int e = 0; e < 4; e++) {
          const float x = acc[i][j][e] + badd;
          const int r = row0 + e;
          if (sel == 2) {
            const int bz = r >> 11;
            const int s  = r & (SS - 1);
            out2[(size_t)bz * (HH * SS) + (size_t)coll * SS + s] = f2bf(x);
          } else {
            oQK[(size_t)r * HH + coll] = f2bf(x);
          }
        }
      }
    }
  } else {
#pragma unroll
    for (int i = 0; i < 4; i++) {
#pragma unroll
      for (int j = 0; j < 4; j++) {
        const int row0 = m0 + wm + i * 16 + cr;
        const int col  = n0 + wn + j * 16 + cc;
#pragma unroll
        for (int e = 0; e < 4; e++) {
          float x = acc[i][j][e];
          const int r = row0 + e;
          if constexpr (MODE == 2) {
            C16[(size_t)r * SS + col] = f2bf(x * 0.03125f);  // 1/sqrt(1024)
          } else {
            C32[(size_t)r * HH + col] = x;                   // fp32 final out
          }
        }
      }
    }
  }
}

// one block (256 threads) per row; each thread owns 8 contiguous columns.
// [r4] causal-aware: spans beyond roundup128(i+1) are never read by MODE 3
// (its kmax caps at the covering 128-tile), so those threads skip the
// load+store entirely. They still join reductions/barriers (no divergence
// hazard on __syncthreads).
__launch_bounds__(256)
__global__ void softmax_causal(uint16_t* __restrict__ Sb) {
  const int rgl = blockIdx.x;          // 0..B*S-1
  const int b = rgl >> 11;
  const int i = rgl & (SS - 1);
  uint16_t* row = Sb + (size_t)b * SS * SS + (size_t)i * SS;
  const int t = threadIdx.x;
  const int base = t * 8;
  const int cover = ((i >> 7) + 1) << 7;   // roundup128(i+1) <= 2048
  const bool act = base < cover;

  uint4 u; u.x = u.y = u.z = u.w = 0u;
  if (act) u = *(const uint4*)(row + base);
  const uint16_t* hs = (const uint16_t*)&u;
  float x[8];
  float lmax = -3.0e38f;
#pragma unroll
  for (int e = 0; e < 8; e++) {
    float f = bf2f(hs[e]);
    x[e] = (act && base + e <= i) ? f : -3.0e38f;
    lmax = fmaxf(lmax, x[e]);
  }
#pragma unroll
  for (int off = 32; off > 0; off >>= 1)
    lmax = fmaxf(lmax, __shfl_down(lmax, off));

  __shared__ float red[8];
  if ((t & 63) == 0) red[t >> 6] = lmax;
  __syncthreads();
  const float m = fmaxf(fmaxf(red[0], red[1]), fmaxf(red[2], red[3]));

  float lsum = 0.f;
#pragma unroll
  for (int e = 0; e < 8; e++) {
    float p = (act && base + e <= i) ? __expf(x[e] - m) : 0.f;
    x[e] = p;
    lsum += p;
  }
#pragma unroll
  for (int off = 32; off > 0; off >>= 1) lsum += __shfl_down(lsum, off);
  if ((t & 63) == 0) red[4 + (t >> 6)] = lsum;
  __syncthreads();
  const float inv = 1.f / (red[4] + red[5] + red[6] + red[7]);

  if (act) {
    alignas(16) uint16_t o[8];
#pragma unroll
    for (int e = 0; e < 8; e++) o[e] = f2bf(x[e] * inv);
    *(uint4*)(row + base) = *(const uint4*)o;
  }
}

extern "C" void kernel_launch(void* const* d_in, const int* in_sizes, int n_in,
                              void* d_out, int out_size, void* d_ws, size_t ws_size,
                              hipStream_t stream) {
  // Inputs fp32 per the reference; output fp32 (reference output dtype).
  const float* x  = (const float*)d_in[0];
  const float* Wq = (const float*)d_in[1];
  const float* bq = (const float*)d_in[2];
  const float* Wk = (const float*)d_in[3];
  const float* bk = (const float*)d_in[4];
  const float* Wv = (const float*)d_in[5];
  const float* bv = (const float*)d_in[6];

  uint16_t* ws = (uint16_t*)d_ws;
  const size_t QKV = (size_t)BB * SS * HH;  // 16,777,216 elems = 32 MB bf16
  uint16_t* Q  = ws;
  uint16_t* Kp = ws + QKV;
  uint16_t* Vt = ws + 2 * QKV;
  uint16_t* Sb = ws + 3 * QKV;              // 8*2048*2048 bf16 = 64 MB
  // xb + converted weights alias the Sb region (dead before MODE 2 writes Sb)
  uint16_t* xb  = Sb;                       // 16,777,216 elems
  uint16_t* Wqb = Sb + QKV;                 // Wq;Wk;Wv contiguous = Wcat 3072x1024
  uint16_t* Wkb = Wqb + (size_t)HH * DD;
  uint16_t* Wvb = Wkb + (size_t)HH * DD;

  dim3 blk(256);
  const int nx = BB * SS * DD;              // 16,777,216
  const int nw = HH * DD;                   // 1,048,576
  cvt_f32_bf16<<<dim3(nx / 2048), blk, 0, stream>>>(x, xb, nx);
  cvt3_f32_bf16<<<dim3(nw / 2048, 3), blk, 0, stream>>>(Wq, Wk, Wv, Wqb, Wkb, Wvb, nw);

  // merged QKV projection: N = 3072
  gemm_bt<0><<<dim3(BB * SS / 128, 3 * HH / 128), blk, 0, stream>>>(
      xb, Wqb, bq, bk, bv, Q, Kp, Vt);
  gemm_bt<2><<<dim3(SS / 128, SS / 128, BB), blk, 0, stream>>>(
      Q, Kp, nullptr, nullptr, nullptr, Sb, nullptr, nullptr);
  softmax_causal<<<dim3(BB * SS), blk, 0, stream>>>(Sb);
  gemm_bt<3><<<dim3(SS / 128, HH / 128, BB), blk, 0, stream>>>(
      Sb, Vt, nullptr, nullptr, nullptr, d_out, nullptr, nullptr);
}

// Round 5
// 419.752 us; speedup vs baseline: 1.0425x; 1.0364x over previous
//
#include <hip/hip_runtime.h>
#include <hip/hip_bf16.h>
#include <cstdint>

#define BB 8
#define SS 2048
#define DD 1024
#define HH 1024

typedef __bf16 bf16x8 __attribute__((ext_vector_type(8)));
typedef float f32x4 __attribute__((ext_vector_type(4)));

// address-space casts for global_load_lds (direct global->LDS DMA)
#define AS1C(p) ((const __attribute__((address_space(1))) void*)(p))
#define AS3(p)  ((__attribute__((address_space(3))) void*)(p))

__device__ __forceinline__ float bf2f(uint16_t h) {
  union { uint32_t u; float f; } v; v.u = ((uint32_t)h) << 16; return v.f;
}
__device__ __forceinline__ uint16_t f2bf(float f) {
  union { float f; uint32_t u; } v; v.f = f;
  uint32_t u = v.u;
  return (uint16_t)((u + 0x7FFFu + ((u >> 16) & 1u)) >> 16);
}

// fp32 -> bf16 (RNE), vectorized 8 elems/thread, grid-stride. n % 8 == 0.
__global__ void cvt_f32_bf16(const float* __restrict__ src,
                             uint16_t* __restrict__ dst, int n) {
  int i = (blockIdx.x * blockDim.x + threadIdx.x) * 8;
  const int stride = gridDim.x * blockDim.x * 8;
  for (; i < n; i += stride) {
    float4 f0 = *(const float4*)(src + i);
    float4 f1 = *(const float4*)(src + i + 4);
    alignas(16) uint16_t o[8];
    o[0] = f2bf(f0.x); o[1] = f2bf(f0.y); o[2] = f2bf(f0.z); o[3] = f2bf(f0.w);
    o[4] = f2bf(f1.x); o[5] = f2bf(f1.y); o[6] = f2bf(f1.z); o[7] = f2bf(f1.w);
    *(uint4*)(dst + i) = *(const uint4*)o;
  }
}

// three same-size fp32->bf16 converts in one dispatch (blockIdx.y selects)
__global__ void cvt3_f32_bf16(const float* __restrict__ s0, const float* __restrict__ s1,
                              const float* __restrict__ s2, uint16_t* __restrict__ d0,
                              uint16_t* __restrict__ d1, uint16_t* __restrict__ d2, int n) {
  const float* src = (blockIdx.y == 0) ? s0 : (blockIdx.y == 1) ? s1 : s2;
  uint16_t* dst = (blockIdx.y == 0) ? d0 : (blockIdx.y == 1) ? d1 : d2;
  int i = (blockIdx.x * blockDim.x + threadIdx.x) * 8;
  const int stride = gridDim.x * blockDim.x * 8;
  for (; i < n; i += stride) {
    float4 f0 = *(const float4*)(src + i);
    float4 f1 = *(const float4*)(src + i + 4);
    alignas(16) uint16_t o[8];
    o[0] = f2bf(f0.x); o[1] = f2bf(f0.y); o[2] = f2bf(f0.z); o[3] = f2bf(f0.w);
    o[4] = f2bf(f1.x); o[5] = f2bf(f1.y); o[6] = f2bf(f1.z); o[7] = f2bf(f1.w);
    *(uint4*)(dst + i) = *(const uint4*)o;
  }
}

// NT GEMM: C[m][n] = sum_k A[m][k] * B[n][k]  (bf16, K-contiguous operands)
// K-loop: BK=64 as two 32-wide LDS buffers (unroll x2) -> 2 barriers per
// 64 K-elems, 32 MFMA per vmcnt drain. Staging via global_load_lds w=16.
// [r5] Core = r0 harness-verified structure (141.9us mode0). History:
//   r2/r3 4-phase 256^2 rewrites: 155/189us (slower; structure loses at
//   NT=16 despite T2 swizzle verified 0 bank conflicts).
//   r4 MODE-0 XCD chunk (tn-fastest): FETCH 143->234MB, 160us — concurrent
//   per-XCD B working set (6MB) overflowed 4MB L2. REVERTED: natural
//   round-robin already keeps the shared 256KB B-panel L2-resident and L3
//   absorbs A re-reads.
// [r5] Modes split into named kernels (gemm_proj/score/pv) for rocprof
//   attribution — top-5 rows previously indistinguishable ("gemm_bt").
// MODE 0: merged QKV projection. B = [Wq;Wk;Wv] (3072x1024). Epilogue picks
//         Q / K / Vt(transposed) + bias by n0>>10 (block-uniform).
// MODE 2: scores = Q Kt / 32 per batch (grid.z). skip tiles tn>tm (causal).
// MODE 3: PV per batch (grid.z). kmax causal. fp32 output.
template <int MODE>
__device__ __forceinline__ void gemm_body(const uint16_t* __restrict__ Aroot,
                                          const uint16_t* __restrict__ Broot,
                                          const float* __restrict__ bq,
                                          const float* __restrict__ bk,
                                          const float* __restrict__ bv,
                                          void* __restrict__ out0,
                                          uint16_t* __restrict__ out1,
                                          uint16_t* __restrict__ out2) {
  constexpr int K   = (MODE == 3) ? 2048 : 1024;
  constexpr int LDA = (MODE == 3) ? 2048 : 1024;
  constexpr int LDB = (MODE == 3) ? 2048 : 1024;

  const int tm = blockIdx.x, tn = blockIdx.y;
  if constexpr (MODE == 2) { if (tn > tm) return; }

  const uint16_t* A = Aroot;
  const uint16_t* Bp = Broot;
  uint16_t* C16 = (uint16_t*)out0;
  float*    C32 = (float*)out0;
  if constexpr (MODE == 2) {
    size_t z = blockIdx.z;
    A  += z * (size_t)(SS * DD);
    Bp += z * (size_t)(SS * DD);
    C16 += z * (size_t)SS * (size_t)SS;
  }
  if constexpr (MODE == 3) {
    size_t z = blockIdx.z;
    A  += z * (size_t)SS * (size_t)SS;
    Bp += z * (size_t)(HH * SS);
    C32 += z * (size_t)(SS * HH);
  }

  const int m0 = tm * 128, n0 = tn * 128;
  int kmax = K;
  if constexpr (MODE == 3) {
    kmax = (tm + 1) * 128;           // multiple of 128 -> multiple of 64
    if (kmax > K) kmax = K;
  }

  __shared__ uint16_t As0[128 * 32];
  __shared__ uint16_t As1[128 * 32];
  __shared__ uint16_t Bs0[128 * 32];
  __shared__ uint16_t Bs1[128 * 32];

  const int tid  = threadIdx.x;
  const int lane = tid & 63;
  const int wv   = tid >> 6;
  const int wm   = (wv & 1) * 64;   // wave's m offset within 128-tile
  const int wn   = (wv >> 1) * 64;  // wave's n offset

  f32x4 acc[4][4];
#pragma unroll
  for (int i = 0; i < 4; i++)
#pragma unroll
    for (int j = 0; j < 4; j++)
#pragma unroll
      for (int e = 0; e < 4; e++) acc[i][j][e] = 0.f;

  // global_load_lds lane mapping within a 16-row chunk:
  // lane l -> row l>>2, elem col (l&3)*8 (16B)
  const int lrow = lane >> 2;
  const int lcol = (lane & 3) * 8;
  const int r0   = wv * 32;         // this wave's 32-row slab

  const uint16_t* gA = A + (size_t)(m0 + r0 + lrow) * LDA + lcol;
  const uint16_t* gB = Bp + (size_t)(n0 + r0 + lrow) * LDB + lcol;

  // fragment indices (A and B operands share the same lane mapping)
  const int fr = lane & 15;
  const int fk = (lane >> 4) * 8;

  for (int k0 = 0; k0 < kmax; k0 += 64) {
    __syncthreads();  // prior ds_reads done before overwrite
    __builtin_amdgcn_global_load_lds(AS1C(gA + k0), AS3(&As0[r0 * 32]), 16, 0, 0);
    __builtin_amdgcn_global_load_lds(AS1C(gA + k0 + 16 * LDA), AS3(&As0[(r0 + 16) * 32]), 16, 0, 0);
    __builtin_amdgcn_global_load_lds(AS1C(gA + k0 + 32), AS3(&As1[r0 * 32]), 16, 0, 0);
    __builtin_amdgcn_global_load_lds(AS1C(gA + k0 + 32 + 16 * LDA), AS3(&As1[(r0 + 16) * 32]), 16, 0, 0);
    __builtin_amdgcn_global_load_lds(AS1C(gB + k0), AS3(&Bs0[r0 * 32]), 16, 0, 0);
    __builtin_amdgcn_global_load_lds(AS1C(gB + k0 + 16 * LDB), AS3(&Bs0[(r0 + 16) * 32]), 16, 0, 0);
    __builtin_amdgcn_global_load_lds(AS1C(gB + k0 + 32), AS3(&Bs1[r0 * 32]), 16, 0, 0);
    __builtin_amdgcn_global_load_lds(AS1C(gB + k0 + 32 + 16 * LDB), AS3(&Bs1[(r0 + 16) * 32]), 16, 0, 0);
    __syncthreads();  // drains vmcnt(0): both 32-chunks staged

    bf16x8 af[4], bfr[4];
#pragma unroll
    for (int i = 0; i < 4; i++)
      af[i] = __builtin_bit_cast(bf16x8, *(const uint4*)&As0[(wm + i * 16 + fr) * 32 + fk]);
#pragma unroll
    for (int j = 0; j < 4; j++)
      bfr[j] = __builtin_bit_cast(bf16x8, *(const uint4*)&Bs0[(wn + j * 16 + fr) * 32 + fk]);
#pragma unroll
    for (int i = 0; i < 4; i++)
#pragma unroll
      for (int j = 0; j < 4; j++)
        acc[i][j] = __builtin_amdgcn_mfma_f32_16x16x32_bf16(af[i], bfr[j], acc[i][j], 0, 0, 0);

#pragma unroll
    for (int i = 0; i < 4; i++)
      af[i] = __builtin_bit_cast(bf16x8, *(const uint4*)&As1[(wm + i * 16 + fr) * 32 + fk]);
#pragma unroll
    for (int j = 0; j < 4; j++)
      bfr[j] = __builtin_bit_cast(bf16x8, *(const uint4*)&Bs1[(wn + j * 16 + fr) * 32 + fk]);
#pragma unroll
    for (int i = 0; i < 4; i++)
#pragma unroll
      for (int j = 0; j < 4; j++)
        acc[i][j] = __builtin_amdgcn_mfma_f32_16x16x32_bf16(af[i], bfr[j], acc[i][j], 0, 0, 0);
  }

  // epilogue: C/D mapping col = lane&15, row = (lane>>4)*4 + e  [verified m89/m91]
  const int cr = (lane >> 4) * 4;
  const int cc = lane & 15;

  if constexpr (MODE == 0) {
    const int sel   = n0 >> 10;            // 0=Q, 1=K, 2=V (block-uniform)
    const int nloc0 = n0 & 1023;
    const float* __restrict__ bsel = (sel == 0) ? bq : (sel == 1) ? bk : bv;
    uint16_t* __restrict__ oQK = (sel == 1) ? out1 : (uint16_t*)out0;
#pragma unroll
    for (int i = 0; i < 4; i++) {
#pragma unroll
      for (int j = 0; j < 4; j++) {
        const int row0 = m0 + wm + i * 16 + cr;
        const int coll = nloc0 + wn + j * 16 + cc;
        const float badd = bsel[coll];
#pragma unroll
        for (int e = 0; e < 4; e++) {
          const float x = acc[i][j][e] + badd;
          const int r = row0 + e;
          if (sel == 2) {
            const int bz = r >> 11;
            const int s  = r & (SS - 1);
            out2[(size_t)bz * (HH * SS) + (size_t)coll * SS + s] = f2bf(x);
          } else {
            oQK[(size_t)r * HH + coll] = f2bf(x);
          }
        }
      }
    }
  } else {
#pragma unroll
    for (int i = 0; i < 4; i++) {
#pragma unroll
      for (int j = 0; j < 4; j++) {
        const int row0 = m0 + wm + i * 16 + cr;
        const int col  = n0 + wn + j * 16 + cc;
#pragma unroll
        for (int e = 0; e < 4; e++) {
          float x = acc[i][j][e];
          const int r = row0 + e;
          if constexpr (MODE == 2) {
            C16[(size_t)r * SS + col] = f2bf(x * 0.03125f);  // 1/sqrt(1024)
          } else {
            C32[(size_t)r * HH + col] = x;                   // fp32 final out
          }
        }
      }
    }
  }
}

// distinct names so rocprof rows attribute time per stage
__launch_bounds__(256, 2)
__global__ void gemm_proj(const uint16_t* __restrict__ A, const uint16_t* __restrict__ B,
                          const float* __restrict__ bq, const float* __restrict__ bk,
                          const float* __restrict__ bv, void* __restrict__ o0,
                          uint16_t* __restrict__ o1, uint16_t* __restrict__ o2) {
  gemm_body<0>(A, B, bq, bk, bv, o0, o1, o2);
}
__launch_bounds__(256, 2)
__global__ void gemm_score(const uint16_t* __restrict__ A, const uint16_t* __restrict__ B,
                           void* __restrict__ o0) {
  gemm_body<2>(A, B, nullptr, nullptr, nullptr, o0, nullptr, nullptr);
}
__launch_bounds__(256, 2)
__global__ void gemm_pv(const uint16_t* __restrict__ A, const uint16_t* __restrict__ B,
                        void* __restrict__ o0) {
  gemm_body<3>(A, B, nullptr, nullptr, nullptr, o0, nullptr, nullptr);
}

// one block (256 threads) per row; each thread owns 8 contiguous columns.
// causal-aware: spans beyond roundup128(i+1) are never read downstream
// (MODE 3 kmax caps at the covering 128-tile), so those threads skip the
// load+store. All threads still join reductions/barriers.
__launch_bounds__(256)
__global__ void softmax_causal(uint16_t* __restrict__ Sb) {
  const int rgl = blockIdx.x;          // 0..B*S-1
  const int b = rgl >> 11;
  const int i = rgl & (SS - 1);
  uint16_t* row = Sb + (size_t)b * SS * SS + (size_t)i * SS;
  const int t = threadIdx.x;
  const int base = t * 8;
  const int cover = ((i >> 7) + 1) << 7;   // roundup128(i+1) <= 2048
  const bool act = base < cover;

  uint4 u; u.x = u.y = u.z = u.w = 0u;
  if (act) u = *(const uint4*)(row + base);
  const uint16_t* hs = (const uint16_t*)&u;
  float x[8];
  float lmax = -3.0e38f;
#pragma unroll
  for (int e = 0; e < 8; e++) {
    float f = bf2f(hs[e]);
    x[e] = (act && base + e <= i) ? f : -3.0e38f;
    lmax = fmaxf(lmax, x[e]);
  }
#pragma unroll
  for (int off = 32; off > 0; off >>= 1)
    lmax = fmaxf(lmax, __shfl_down(lmax, off));

  __shared__ float red[8];
  if ((t & 63) == 0) red[t >> 6] = lmax;
  __syncthreads();
  const float m = fmaxf(fmaxf(red[0], red[1]), fmaxf(red[2], red[3]));

  float lsum = 0.f;
#pragma unroll
  for (int e = 0; e < 8; e++) {
    float p = (act && base + e <= i) ? __expf(x[e] - m) : 0.f;
    x[e] = p;
    lsum += p;
  }
#pragma unroll
  for (int off = 32; off > 0; off >>= 1) lsum += __shfl_down(lsum, off);
  if ((t & 63) == 0) red[4 + (t >> 6)] = lsum;
  __syncthreads();
  const float inv = 1.f / (red[4] + red[5] + red[6] + red[7]);

  if (act) {
    alignas(16) uint16_t o[8];
#pragma unroll
    for (int e = 0; e < 8; e++) o[e] = f2bf(x[e] * inv);
    *(uint4*)(row + base) = *(const uint4*)o;
  }
}

extern "C" void kernel_launch(void* const* d_in, const int* in_sizes, int n_in,
                              void* d_out, int out_size, void* d_ws, size_t ws_size,
                              hipStream_t stream) {
  // Inputs fp32 per the reference; output fp32 (reference output dtype).
  const float* x  = (const float*)d_in[0];
  const float* Wq = (const float*)d_in[1];
  const float* bq = (const float*)d_in[2];
  const float* Wk = (const float*)d_in[3];
  const float* bk = (const float*)d_in[4];
  const float* Wv = (const float*)d_in[5];
  const float* bv = (const float*)d_in[6];

  uint16_t* ws = (uint16_t*)d_ws;
  const size_t QKV = (size_t)BB * SS * HH;  // 16,777,216 elems = 32 MB bf16
  uint16_t* Q  = ws;
  uint16_t* Kp = ws + QKV;
  uint16_t* Vt = ws + 2 * QKV;
  uint16_t* Sb = ws + 3 * QKV;              // 8*2048*2048 bf16 = 64 MB
  // xb + converted weights alias the Sb region (dead before MODE 2 writes Sb)
  uint16_t* xb  = Sb;                       // 16,777,216 elems
  uint16_t* Wqb = Sb + QKV;                 // Wq;Wk;Wv contiguous = Wcat 3072x1024
  uint16_t* Wkb = Wqb + (size_t)HH * DD;
  uint16_t* Wvb = Wkb + (size_t)HH * DD;

  dim3 blk(256);
  const int nx = BB * SS * DD;              // 16,777,216
  const int nw = HH * DD;                   // 1,048,576
  cvt_f32_bf16<<<dim3(nx / 2048), blk, 0, stream>>>(x, xb, nx);
  cvt3_f32_bf16<<<dim3(nw / 2048, 3), blk, 0, stream>>>(Wq, Wk, Wv, Wqb, Wkb, Wvb, nw);

  // merged QKV projection: N = 3072
  gemm_proj<<<dim3(BB * SS / 128, 3 * HH / 128), blk, 0, stream>>>(
      xb, Wqb, bq, bk, bv, Q, Kp, Vt);
  gemm_score<<<dim3(SS / 128, SS / 128, BB), blk, 0, stream>>>(Q, Kp, Sb);
  softmax_causal<<<dim3(BB * SS), blk, 0, stream>>>(Sb);
  gemm_pv<<<dim3(SS / 128, HH / 128, BB), blk, 0, stream>>>(Sb, Vt, d_out);
}